// Round 15
// baseline (149.864 us; speedup 1.0000x reference)
//
#include <hip/hip_runtime.h>
#include <cstdint>
#include <cstddef>

// Problem constants
#define SEQ 2048
#define HID 1024
#define NHEAD 16
#define HDIM 64

typedef _Float16 f16;
typedef f16 half8 __attribute__((ext_vector_type(8)));
typedef f16 half4 __attribute__((ext_vector_type(4)));
typedef f16 half2_ __attribute__((ext_vector_type(2)));
typedef float f32x4 __attribute__((ext_vector_type(4)));

// async global->LDS, 16B per lane (wave-uniform LDS base + lane*16)
#define ASYNC_COPY16(g, l)                                                    \
  __builtin_amdgcn_global_load_lds(                                           \
      (const __attribute__((address_space(1))) void*)(const void*)(g),        \
      (__attribute__((address_space(3))) void*)(void*)(l), 16, 0, 0)

// ---------------------------------------------------------------------------
// Prologue (768 blocks): transpose-cast w_attn in 64x64 tiles. The h-cast is
// gone (gemm1 consumes fp32 H directly, casting during A-staging); the wp
// transpose rides inside the attn dispatch.
__global__ __launch_bounds__(256) void prologue(
    const float* __restrict__ wa, f16* __restrict__ waT) {
  const int b = blockIdx.x, tid = threadIdx.x;
  const int bx = b % 48, by = b / 48;
  __shared__ float tile[64][65];
  const int tx = tid & 63, ty = tid >> 6;  // 64 x 4
  const int c0 = bx * 64, r0 = by * 64;
#pragma unroll
  for (int i = 0; i < 64; i += 4)
    tile[ty + i][tx] = wa[(size_t)(r0 + ty + i) * 3072 + c0 + tx];
  __syncthreads();
#pragma unroll
  for (int i = 0; i < 64; i += 4)
    waT[(size_t)(c0 + ty + i) * 1024 + r0 + tx] = (f16)tile[tx][ty + i];
}

// ---------------------------------------------------------------------------
// GEMM1: C = A32[M,K] * Bt[N,K]^T + bias -> f16. BM=64 x BN=128, BK=64,
// 2-phase double-buffered pipeline. A is fp32, reg-staged with cast
// (T14 issue-early / write-late); LDS layout keeps the same swizzle
// invariant LDS[row][s] = global chunk s^(row&7), so fragment reads are
// identical to the f16 path. B (waT) stays global_load_lds with
// pre-swizzled source (rule 21).
__global__ __launch_bounds__(256) void gemm_h(
    const float* __restrict__ A, const f16* __restrict__ Bt,
    const float* __restrict__ bias, f16* __restrict__ Cout, int M, int N,
    int K) {
  constexpr int BM = 64, BN = 128;
  constexpr int FM = BM / 32, FN = BN / 32;
  __shared__ __align__(16) f16 sA[2][BM * 64];
  __shared__ __align__(16) f16 sB[2][BN * 64];
  const int tid = threadIdx.x;
  const int wave = tid >> 6, lane = tid & 63;
  const int quad = lane >> 4, l16 = lane & 15;
  const int m0 = blockIdx.y * BM, n0 = blockIdx.x * BN;
  const int wm = (wave >> 1) * (BM / 2), wn = (wave & 1) * (BN / 2);
  const int rowA = lane >> 3;             // staging row-within-8 (B path)
  const int chunkA = (lane & 7) ^ rowA;   // XOR-swizzled 16B k-chunk (B path)
  const int r7 = l16 & 7;                 // row&7 for fragment reads

  // A reg-staging mapping: thread -> (row 0..63, two 8-f16 slots)
  const int arow = tid >> 2;              // 0..63
  const int as0 = (tid & 3) * 2;          // slots as0, as0+1
  float4 areg[4];

  auto loadA = [&](int k0) {
#pragma unroll
    for (int s = 0; s < 2; s++) {
      const int chunk = (as0 + s) ^ (arow & 7);
      const float* src = A + (size_t)(m0 + arow) * K + k0 + chunk * 8;
      areg[s * 2] = *(const float4*)(src);
      areg[s * 2 + 1] = *(const float4*)(src + 4);
    }
  };
  auto writeA = [&](int buf) {
#pragma unroll
    for (int s = 0; s < 2; s++) {
      half8 o;
      o[0] = (f16)areg[s * 2].x; o[1] = (f16)areg[s * 2].y;
      o[2] = (f16)areg[s * 2].z; o[3] = (f16)areg[s * 2].w;
      o[4] = (f16)areg[s * 2 + 1].x; o[5] = (f16)areg[s * 2 + 1].y;
      o[6] = (f16)areg[s * 2 + 1].z; o[7] = (f16)areg[s * 2 + 1].w;
      *(half8*)&sA[buf][arow * 64 + (as0 + s) * 8] = o;
    }
  };
  auto stageB = [&](int buf, int k0) {
#pragma unroll
    for (int r = wave; r < BN / 8; r += 4)
      ASYNC_COPY16(Bt + (size_t)(n0 + r * 8 + rowA) * K + k0 + chunkA * 8,
                   &sB[buf][r * 512]);
  };

  f32x4 acc[FM][FN] = {};

  loadA(0);
  stageB(0, 0);
  writeA(0);
  __syncthreads();  // drains vmcnt (B) + lgkmcnt (A writes)
  const int NT = K / 64;
  for (int t = 0; t < NT; ++t) {
    const int cur = t & 1;
    if (t + 1 < NT) {
      loadA((t + 1) * 64);          // issue early (hides under MFMA)
      stageB(cur ^ 1, (t + 1) * 64);
    }

#pragma unroll
    for (int hh = 0; hh < 2; hh++) {
      half8 af[FM], bf[FN];
#pragma unroll
      for (int i = 0; i < FM; i++)
        af[i] = *(const half8*)&sA[cur][(wm + i * 16 + l16) * 64 +
                                        (((hh << 2) | quad) ^ r7) * 8];
#pragma unroll
      for (int j = 0; j < FN; j++)
        bf[j] = *(const half8*)&sB[cur][(wn + j * 16 + l16) * 64 +
                                        (((hh << 2) | quad) ^ r7) * 8];
#pragma unroll
      for (int i = 0; i < FM; i++)
#pragma unroll
        for (int j = 0; j < FN; j++)
          acc[i][j] = __builtin_amdgcn_mfma_f32_16x16x32_f16(
              af[i], bf[j], acc[i][j], 0, 0, 0);
    }
    if (t + 1 < NT) writeA(cur ^ 1);  // write late (off critical path)
    __syncthreads();
  }

#pragma unroll
  for (int i = 0; i < FM; i++) {
    int row = m0 + wm + i * 16 + quad * 4;
#pragma unroll
    for (int j = 0; j < FN; j++) {
      int col = n0 + wn + j * 16 + l16;
      float bv = bias[col];
#pragma unroll
      for (int r = 0; r < 4; r++)
        Cout[(size_t)(row + r) * N + col] = (f16)(acc[i][j][r] + bv);
    }
  }
}

// ---------------------------------------------------------------------------
// GEMM2: C = A[M,K] * Bt[N,K]^T + bias -> fp32 ; 64x64 tile, BK=64, 2-phase
// double-buffered pipeline, XOR swizzle both sides (rule 21). (r9 version.)
template <int BM, int BN>
__global__ __launch_bounds__(256) void gemm_f16(
    const f16* __restrict__ A, const f16* __restrict__ Bt,
    const float* __restrict__ bias, float* __restrict__ Cout, int M, int N,
    int K) {
  constexpr int FM = BM / 32, FN = BN / 32;
  __shared__ __align__(16) f16 sA[2][BM * 64];
  __shared__ __align__(16) f16 sB[2][BN * 64];
  const int tid = threadIdx.x;
  const int wave = tid >> 6, lane = tid & 63;
  const int quad = lane >> 4, l16 = lane & 15;
  const int m0 = blockIdx.y * BM, n0 = blockIdx.x * BN;
  const int wm = (wave >> 1) * (BM / 2), wn = (wave & 1) * (BN / 2);
  const int rowA = lane >> 3;
  const int chunkA = (lane & 7) ^ rowA;
  const int r7 = l16 & 7;

  auto stage = [&](int buf, int k0) {
#pragma unroll
    for (int r = wave; r < BM / 8; r += 4)
      ASYNC_COPY16(A + (size_t)(m0 + r * 8 + rowA) * K + k0 + chunkA * 8,
                   &sA[buf][r * 512]);
#pragma unroll
    for (int r = wave; r < BN / 8; r += 4)
      ASYNC_COPY16(Bt + (size_t)(n0 + r * 8 + rowA) * K + k0 + chunkA * 8,
                   &sB[buf][r * 512]);
  };

  f32x4 acc[FM][FN] = {};

  stage(0, 0);
  __syncthreads();
  const int NT = K / 64;
  for (int t = 0; t < NT; ++t) {
    const int cur = t & 1;
    if (t + 1 < NT) stage(cur ^ 1, (t + 1) * 64);

#pragma unroll
    for (int hh = 0; hh < 2; hh++) {
      half8 af[FM], bf[FN];
#pragma unroll
      for (int i = 0; i < FM; i++)
        af[i] = *(const half8*)&sA[cur][(wm + i * 16 + l16) * 64 +
                                        (((hh << 2) | quad) ^ r7) * 8];
#pragma unroll
      for (int j = 0; j < FN; j++)
        bf[j] = *(const half8*)&sB[cur][(wn + j * 16 + l16) * 64 +
                                        (((hh << 2) | quad) ^ r7) * 8];
#pragma unroll
      for (int i = 0; i < FM; i++)
#pragma unroll
        for (int j = 0; j < FN; j++)
          acc[i][j] = __builtin_amdgcn_mfma_f32_16x16x32_f16(
              af[i], bf[j], acc[i][j], 0, 0, 0);
    }
    __syncthreads();
  }

#pragma unroll
  for (int i = 0; i < FM; i++) {
    int row = m0 + wm + i * 16 + quad * 4;
#pragma unroll
    for (int j = 0; j < FN; j++) {
      int col = n0 + wn + j * 16 + l16;
      float bv = bias[col];
#pragma unroll
      for (int r = 0; r < 4; r++)
        Cout[(size_t)(row + r) * N + col] = acc[i][j][r] + bv;
    }
  }
}

// ---------------------------------------------------------------------------
// Split-K causal flash attention (r9 main loop). Blocks [0,640): attention;
// blocks [640,896): wp transpose-cast riders (wpT consumed only after the
// kernel boundary). Shared memory aliased via one char[] block.
#define LROW 72
__global__ __launch_bounds__(256, 3) void attn_split(
    const f16* __restrict__ qkv, f16* __restrict__ out,
    f16* __restrict__ Opart, float* __restrict__ ml,
    const float* __restrict__ wp, f16* __restrict__ wpT) {
  __shared__ __align__(16) char smem[37376];  // max(attn 37376, tile 16640)

  if (blockIdx.x >= 640) {  // wp transpose rider: 256 blocks, 64x64 tiles
    const int t = blockIdx.x - 640, tid = threadIdx.x;
    const int bx = t & 15, by = t >> 4;
    float* tile = (float*)smem;  // [64][65]
    const int tx = tid & 63, ty = tid >> 6;
    const int c0 = bx * 64, r0 = by * 64;
#pragma unroll
    for (int i = 0; i < 64; i += 4)
      tile[(ty + i) * 65 + tx] = wp[(size_t)(r0 + ty + i) * 1024 + c0 + tx];
    __syncthreads();
#pragma unroll
    for (int i = 0; i < 64; i += 4)
      wpT[(size_t)(c0 + ty + i) * 1024 + r0 + tx] = (f16)tile[tx * 65 + ty + i];
    return;
  }

  const int b = (blockIdx.x & 7) * 80 + (blockIdx.x >> 3);
  const int h = b / 40;
  const int t = b % 40;
  int m, c, nc;
  if (t < 4)       { m = t;                 c = 0;      nc = 1; }
  else if (t < 12) { int u = t - 4;  m = 4 + (u >> 1);  c = u & 1; nc = 2; }
  else if (t < 24) { int u = t - 12; m = 8 + u / 3;     c = u % 3; nc = 3; }
  else             { int u = t - 24; m = 12 + (u >> 2); c = u & 3; nc = 4; }
  const int q0 = m * 128;
  const int T = 2 * m + 2;             // k64 tiles needed (causal)
  const int kt0 = c * 8;
  const int kt1 = (kt0 + 8 < T) ? kt0 + 8 : T;
  const int maskFrom = 2 * m;          // diagonal-overlap tiles

  f16* sK = (f16*)smem;                       // [64][LROW]
  f16* sVt = sK + 64 * LROW;                  // [64][LROW]
  f16* sP = sVt + 64 * LROW;                  // [4][32*LROW]

  const int tid = threadIdx.x;
  const int wave = tid >> 6, lane = tid & 63;
  const int quad = lane >> 4, l16 = lane & 15;

  // Q fragments for both q-groups, pre-scaled by sm_scale*log2(e)
  const f16 qs = (f16)0.18033688f;  // 0.125 * log2(e)
  half8 qf[2][2];
#pragma unroll
  for (int g = 0; g < 2; g++) {
    const f16* qb = qkv + (size_t)(q0 + wave * 32 + g * 16 + l16) * 3072 +
                    h * HDIM + quad * 8;
    qf[g][0] = *(const half8*)qb;
    qf[g][1] = *(const half8*)(qb + 32);
#pragma unroll
    for (int j = 0; j < 8; j++) { qf[g][0][j] *= qs; qf[g][1][j] *= qs; }
  }

  const f16* kbase = qkv + HID + h * HDIM;
  const f16* vbase = qkv + 2 * HID + h * HDIM;
  const int ks_row = tid >> 3, ks_cc = tid & 7;
  const int vs_d = tid & 63, vs_g = tid >> 6;

  f32x4 o[2][4] = {};
  float m_i[2] = {-1e30f, -1e30f}, l_i[2] = {0.f, 0.f};
  half8 kreg[2], vreg[2];

  auto prefetch = [&](int kt) {
    const int k0 = kt * 64;
#pragma unroll
    for (int i = 0; i < 2; i++) {
      kreg[i] = *(const half8*)(kbase + (size_t)(k0 + ks_row + i * 32) * 3072 +
                                ks_cc * 8);
      half8 col;
#pragma unroll
      for (int j = 0; j < 8; j++)
        col[j] = vbase[(size_t)(k0 + (vs_g + i * 4) * 8 + j) * 3072 + vs_d];
      vreg[i] = col;
    }
  };

  prefetch(kt0);
  for (int kt = kt0; kt < kt1; kt++) {
    const int k0 = kt * 64;
#pragma unroll
    for (int i = 0; i < 2; i++) {
      *(half8*)&sK[(ks_row + i * 32) * LROW + ks_cc * 8] = kreg[i];
      *(half8*)&sVt[vs_d * LROW + (vs_g + i * 4) * 8] = vreg[i];
    }
    __syncthreads();
    if (kt + 1 < kt1) prefetch(kt + 1);

    // S^T = K Q^T ; K-frag reads shared across both q-groups
    f32x4 sacc[2][4] = {};
#pragma unroll
    for (int kb = 0; kb < 4; kb++) {
      half8 kf0 = *(const half8*)&sK[(kb * 16 + l16) * LROW + quad * 8];
      half8 kf1 = *(const half8*)&sK[(kb * 16 + l16) * LROW + 32 + quad * 8];
#pragma unroll
      for (int g = 0; g < 2; g++) {
        sacc[g][kb] = __builtin_amdgcn_mfma_f32_16x16x32_f16(kf0, qf[g][0],
                                                             sacc[g][kb], 0, 0, 0);
        sacc[g][kb] = __builtin_amdgcn_mfma_f32_16x16x32_f16(kf1, qf[g][1],
                                                             sacc[g][kb], 0, 0, 0);
      }
    }
    // causal mask on diagonal-overlap tiles
    if (kt >= maskFrom) {
#pragma unroll
      for (int g = 0; g < 2; g++) {
        const int qg = q0 + wave * 32 + g * 16 + l16;
#pragma unroll
        for (int kb = 0; kb < 4; kb++) {
          int kg = k0 + kb * 16 + quad * 4;
#pragma unroll
          for (int r = 0; r < 4; r++)
            if (kg + r > qg) sacc[g][kb][r] = -1e30f;
        }
      }
    }
    // online softmax per q-group, defer-max (skip rescale unless the tile
    // max exceeds the running max by >8 in log2 units; P then bounded 2^8)
#pragma unroll
    for (int g = 0; g < 2; g++) {
      float mx = -1e30f;
#pragma unroll
      for (int kb = 0; kb < 4; kb++)
#pragma unroll
        for (int r = 0; r < 4; r++) mx = fmaxf(mx, sacc[g][kb][r]);
      mx = fmaxf(mx, __shfl_xor(mx, 16));
      mx = fmaxf(mx, __shfl_xor(mx, 32));
      if (!__all(mx <= m_i[g] + 8.f)) {
        const float mnew = fmaxf(m_i[g], mx);
        const float alpha = exp2f(m_i[g] - mnew);
        l_i[g] *= alpha;
#pragma unroll
        for (int j = 0; j < 4; j++)
#pragma unroll
          for (int r = 0; r < 4; r++) o[g][j][r] *= alpha;
        m_i[g] = mnew;
      }
      float rs = 0.f;
#pragma unroll
      for (int kb = 0; kb < 4; kb++)
#pragma unroll
        for (int r = 0; r < 4; r++) {
          float p = exp2f(sacc[g][kb][r] - m_i[g]);
          sacc[g][kb][r] = p;
          rs += p;
        }
      rs += __shfl_xor(rs, 16);
      rs += __shfl_xor(rs, 32);
      l_i[g] += rs;
      // P store (wave-private LDS, in-order within wave) — half4 b64 writes
      f16* pw = &sP[wave * 32 * LROW + (g * 16 + l16) * LROW];
#pragma unroll
      for (int kb = 0; kb < 4; kb++) {
        half4 pv;
#pragma unroll
        for (int r = 0; r < 4; r++) pv[r] = (f16)sacc[g][kb][r];
        *(half4*)&pw[kb * 16 + quad * 4] = pv;
      }
    }
    // O^T += V^T P^T ; P fragments hoisted (j-invariant), V-frag reads
    // shared across both q-groups
    half8 pf[2][2];
#pragma unroll
    for (int g = 0; g < 2; g++) {
      pf[g][0] = *(const half8*)&sP[wave * 32 * LROW + (g * 16 + l16) * LROW + quad * 8];
      pf[g][1] = *(const half8*)&sP[wave * 32 * LROW + (g * 16 + l16) * LROW + 32 + quad * 8];
    }
#pragma unroll
    for (int j = 0; j < 4; j++) {
      half8 vf0 = *(const half8*)&sVt[(j * 16 + l16) * LROW + quad * 8];
      half8 vf1 = *(const half8*)&sVt[(j * 16 + l16) * LROW + 32 + quad * 8];
#pragma unroll
      for (int g = 0; g < 2; g++) {
        o[g][j] = __builtin_amdgcn_mfma_f32_16x16x32_f16(vf0, pf[g][0], o[g][j], 0, 0, 0);
        o[g][j] = __builtin_amdgcn_mfma_f32_16x16x32_f16(vf1, pf[g][1], o[g][j], 0, 0, 0);
      }
    }
    __syncthreads();
  }

  if (nc == 1) {
#pragma unroll
    for (int g = 0; g < 2; g++) {
      const float inv = 1.f / l_i[g];
      f16* orow =
          out + (size_t)(q0 + wave * 32 + g * 16 + l16) * HID + h * HDIM;
#pragma unroll
      for (int j = 0; j < 4; j++) {
        half4 hv;
#pragma unroll
        for (int r = 0; r < 4; r++) hv[r] = (f16)(o[g][j][r] * inv);
        *(half4*)&orow[j * 16 + quad * 4] = hv;
      }
    }
  } else {
    // per-head 36 slots: m4..7 ->(m-4)*2, m8..11 ->8+(m-8)*3, m12..15 ->20+(m-12)*4
    int base;
    if (m < 8)       base = (m - 4) * 2;
    else if (m < 12) base = 8 + (m - 8) * 3;
    else             base = 20 + (m - 12) * 4;
    const int slot = h * 36 + base + c;
#pragma unroll
    for (int g = 0; g < 2; g++) {
      const int qrow = wave * 32 + g * 16 + l16;
      f16* op = Opart + (size_t)slot * 8192 + qrow * 64;
#pragma unroll
      for (int j = 0; j < 4; j++) {
        half4 hv;
#pragma unroll
        for (int r = 0; r < 4; r++) hv[r] = (f16)o[g][j][r];
        *(half4*)&op[j * 16 + quad * 4] = hv;
      }
      if (quad == 0) {
        ml[slot * 256 + qrow] = m_i[g];
        ml[slot * 256 + 128 + qrow] = l_i[g];
      }
    }
  }
}

// ---------------------------------------------------------------------------
// Combine partials for m >= 4 (slim: 1536 blocks, 4 d's per thread,
// half4-vectorized Opart loads and out store).
__global__ __launch_bounds__(256) void attn_combine(
    const f16* __restrict__ Opart, const float* __restrict__ ml,
    f16* __restrict__ out) {
  int idx = blockIdx.x * 256 + threadIdx.x;
  int d4 = (idx & 15) * 4;
  int row = (idx >> 4) & 127;
  int rest = idx >> 11;      // 0..191
  int mi = rest % 12;        // m-4
  int h = rest / 12;
  int m = 4 + mi;
  int nc = (mi < 4) ? 2 : (mi < 8) ? 3 : 4;
  int base = (mi < 4) ? mi * 2 : (mi < 8) ? 8 + (mi - 4) * 3 : 20 + (mi - 8) * 4;
  int slot0 = h * 36 + base;

  float mm[4], ll[4];
  float M = -1e30f;
#pragma unroll
  for (int cc = 0; cc < 4; cc++)
    if (cc < nc) {
      mm[cc] = ml[(slot0 + cc) * 256 + row];
      ll[cc] = ml[(slot0 + cc) * 256 + 128 + row];
      M = fmaxf(M, mm[cc]);
    }
  float L = 0.f, acc[4] = {0.f, 0.f, 0.f, 0.f};
#pragma unroll
  for (int cc = 0; cc < 4; cc++)
    if (cc < nc) {
      float w = exp2f(mm[cc] - M);
      L += w * ll[cc];
      half4 ov = *(const half4*)&Opart[(size_t)(slot0 + cc) * 8192 +
                                       row * 64 + d4];
#pragma unroll
      for (int r = 0; r < 4; r++) acc[r] += w * (float)ov[r];
    }
  const float invL = 1.f / L;
  half4 hv;
#pragma unroll
  for (int r = 0; r < 4; r++) hv[r] = (f16)(acc[r] * invL);
  *(half4*)&out[(size_t)(m * 128 + row) * HID + h * HDIM + d4] = hv;
}

// ---------------------------------------------------------------------------
extern "C" void kernel_launch(void* const* d_in, const int* in_sizes, int n_in,
                              void* d_out, int out_size, void* d_ws,
                              size_t ws_size, hipStream_t stream) {
  const float* h = (const float*)d_in[0];    // [2048,1024]
  const float* wa = (const float*)d_in[1];   // [1024,3072]
  const float* ba = (const float*)d_in[2];   // [3072]
  const float* wp = (const float*)d_in[3];   // [1024,1024]
  const float* bp = (const float*)d_in[4];   // [1024]
  float* out = (float*)d_out;                // [2048,1024] fp32

  char* ws = (char*)d_ws;
  f16* waT = (f16*)(ws + (4u << 20));          //  6 MiB, ends 10 MiB (dead after GEMM1)
  f16* wpT = (f16*)(ws + (10u << 20));         //  2 MiB (written by attn riders)
  f16* qkv = (f16*)(ws + (12u << 20));         // 12 MiB
  f16* attn = (f16*)(ws + (24u << 20));        //  4 MiB
  f16* Opart = (f16*)(ws);                     // 576*8192*2 = 9.44 MB
  float* mlbuf = (float*)(ws + 9437184);       // 576*256*4 (inside dead waT, safe post-GEMM1)

  // wa transpose only (h16 cast removed — gemm_h reads fp32 H directly)
  prologue<<<768, 256, 0, stream>>>(wa, waT);
  // QKV = H @ Wattn + b -> f16 ; 64x128 tiles BK=64 2-phase, A reg-staged
  // fp32->f16, 768 blocks
  gemm_h<<<dim3(24, 32), 256, 0, stream>>>(h, waT, ba, qkv, SEQ, 3 * HID, HID);
  // split-K causal attention (640 blocks) + wp-transpose riders (256 blocks)
  attn_split<<<896, 256, 0, stream>>>(qkv, attn, Opart, mlbuf, wp, wpT);
  attn_combine<<<1536, 256, 0, stream>>>(Opart, mlbuf, attn);
  // OUT = attn @ Wproj + b -> fp32 ; 64x64 tiles BK=64 2-phase, 512 blocks
  gemm_f16<64, 64><<<dim3(16, 32), 256, 0, stream>>>(
      attn, wpT, bp, out, SEQ, HID, HID);
}

// Round 16
// 143.639 us; speedup vs baseline: 1.0433x; 1.0433x over previous
//
#include <hip/hip_runtime.h>
#include <cstdint>
#include <cstddef>

// Problem constants
#define SEQ 2048
#define HID 1024
#define NHEAD 16
#define HDIM 64

typedef _Float16 f16;
typedef f16 half8 __attribute__((ext_vector_type(8)));
typedef f16 half4 __attribute__((ext_vector_type(4)));
typedef f16 half2_ __attribute__((ext_vector_type(2)));
typedef float f32x4 __attribute__((ext_vector_type(4)));

// async global->LDS, 16B per lane (wave-uniform LDS base + lane*16)
#define ASYNC_COPY16(g, l)                                                    \
  __builtin_amdgcn_global_load_lds(                                           \
      (const __attribute__((address_space(1))) void*)(const void*)(g),        \
      (__attribute__((address_space(3))) void*)(void*)(l), 16, 0, 0)

// ---------------------------------------------------------------------------
// Prologue (1792 blocks): [0,768) transpose-cast w_attn in 64x64 tiles,
// [768,1792) cast hidden fp32->f16 (8 elems/thread). The h16 pre-cast pays:
// gemm1's 24 column-strips re-read A, and f16 halves that traffic (r15
// lesson — folding the cast into gemm1 regressed). The wp transpose rides
// inside the attn dispatch.
__global__ __launch_bounds__(256) void prologue(
    const float* __restrict__ h, const float* __restrict__ wa,
    f16* __restrict__ h16, f16* __restrict__ waT) {
  const int b = blockIdx.x, tid = threadIdx.x;
  if (b >= 768) {  // cast h
    int i = ((b - 768) * 256 + tid) * 8;
    float4 v0 = *(const float4*)(h + i);
    float4 v1 = *(const float4*)(h + i + 4);
    half8 o;
    o[0] = (f16)v0.x; o[1] = (f16)v0.y; o[2] = (f16)v0.z; o[3] = (f16)v0.w;
    o[4] = (f16)v1.x; o[5] = (f16)v1.y; o[6] = (f16)v1.z; o[7] = (f16)v1.w;
    *(half8*)(h16 + i) = o;
    return;
  }
  // transpose-cast wa[1024][3072] -> waT[3072][1024], 64x64 tiles
  const int bx = b % 48, by = b / 48;
  __shared__ float tile[64][65];
  const int tx = tid & 63, ty = tid >> 6;  // 64 x 4
  const int c0 = bx * 64, r0 = by * 64;
#pragma unroll
  for (int i = 0; i < 64; i += 4)
    tile[ty + i][tx] = wa[(size_t)(r0 + ty + i) * 3072 + c0 + tx];
  __syncthreads();
#pragma unroll
  for (int i = 0; i < 64; i += 4)
    waT[(size_t)(c0 + ty + i) * 1024 + r0 + tx] = (f16)tile[tx][ty + i];
}

// ---------------------------------------------------------------------------
// C = A[M,K] * Bt[N,K]^T + bias ; BM x BN tile, BK=64, 4 waves as 2x2.
// 2-phase pipeline (double-buffered LDS, next-tile global_load_lds issued
// before computing current tile, ONE barrier per K-step). XOR swizzle
// (rule 21: pre-swizzled global source + swizzled fragment read).
template <int BM, int BN, bool OUT16>
__global__ __launch_bounds__(256) void gemm_f16(
    const f16* __restrict__ A, const f16* __restrict__ Bt,
    const float* __restrict__ bias, void* __restrict__ Cout, int M, int N,
    int K) {
  constexpr int FM = BM / 32, FN = BN / 32;
  __shared__ __align__(16) f16 sA[2][BM * 64];
  __shared__ __align__(16) f16 sB[2][BN * 64];
  const int tid = threadIdx.x;
  const int wave = tid >> 6, lane = tid & 63;
  const int quad = lane >> 4, l16 = lane & 15;
  const int m0 = blockIdx.y * BM, n0 = blockIdx.x * BN;
  const int wm = (wave >> 1) * (BM / 2), wn = (wave & 1) * (BN / 2);
  const int rowA = lane >> 3;             // 0..7 within the 8-row group
  const int chunkA = (lane & 7) ^ rowA;   // XOR-swizzled 16B k-chunk
  const int r7 = l16 & 7;                 // row&7 for fragment reads

  auto stage = [&](int buf, int k0) {
#pragma unroll
    for (int r = wave; r < BM / 8; r += 4)
      ASYNC_COPY16(A + (size_t)(m0 + r * 8 + rowA) * K + k0 + chunkA * 8,
                   &sA[buf][r * 512]);
#pragma unroll
    for (int r = wave; r < BN / 8; r += 4)
      ASYNC_COPY16(Bt + (size_t)(n0 + r * 8 + rowA) * K + k0 + chunkA * 8,
                   &sB[buf][r * 512]);
  };

  f32x4 acc[FM][FN] = {};

  stage(0, 0);
  __syncthreads();  // implicit vmcnt(0) drain: buffer 0 ready
  const int NT = K / 64;
  for (int t = 0; t < NT; ++t) {
    const int cur = t & 1;
    if (t + 1 < NT) stage(cur ^ 1, (t + 1) * 64);  // overlaps with compute

#pragma unroll
    for (int hh = 0; hh < 2; hh++) {
      half8 af[FM], bf[FN];
#pragma unroll
      for (int i = 0; i < FM; i++)
        af[i] = *(const half8*)&sA[cur][(wm + i * 16 + l16) * 64 +
                                        (((hh << 2) | quad) ^ r7) * 8];
#pragma unroll
      for (int j = 0; j < FN; j++)
        bf[j] = *(const half8*)&sB[cur][(wn + j * 16 + l16) * 64 +
                                        (((hh << 2) | quad) ^ r7) * 8];
#pragma unroll
      for (int i = 0; i < FM; i++)
#pragma unroll
        for (int j = 0; j < FN; j++)
          acc[i][j] = __builtin_amdgcn_mfma_f32_16x16x32_f16(
              af[i], bf[j], acc[i][j], 0, 0, 0);
    }
    __syncthreads();
  }

#pragma unroll
  for (int i = 0; i < FM; i++) {
    int row = m0 + wm + i * 16 + quad * 4;
#pragma unroll
    for (int j = 0; j < FN; j++) {
      int col = n0 + wn + j * 16 + l16;
      float bv = bias[col];
#pragma unroll
      for (int r = 0; r < 4; r++) {
        float v = acc[i][j][r] + bv;
        if (OUT16)
          ((f16*)Cout)[(size_t)(row + r) * N + col] = (f16)v;
        else
          ((float*)Cout)[(size_t)(row + r) * N + col] = v;
      }
    }
  }
}

// ---------------------------------------------------------------------------
// Split-K causal flash attention (r9 main loop, session best). Blocks
// [0,640): attention; blocks [640,896): wp transpose-cast riders (fill idle
// CUs during attn's imbalanced tail; wpT consumed only after the kernel
// boundary). Shared memory aliased via one char[] block.
#define LROW 72
__global__ __launch_bounds__(256, 3) void attn_split(
    const f16* __restrict__ qkv, f16* __restrict__ out,
    f16* __restrict__ Opart, float* __restrict__ ml,
    const float* __restrict__ wp, f16* __restrict__ wpT) {
  __shared__ __align__(16) char smem[37376];  // max(attn 37376, tile 16640)

  if (blockIdx.x >= 640) {  // wp transpose rider: 256 blocks, 64x64 tiles
    const int t = blockIdx.x - 640, tid = threadIdx.x;
    const int bx = t & 15, by = t >> 4;
    float* tile = (float*)smem;  // [64][65]
    const int tx = tid & 63, ty = tid >> 6;
    const int c0 = bx * 64, r0 = by * 64;
#pragma unroll
    for (int i = 0; i < 64; i += 4)
      tile[(ty + i) * 65 + tx] = wp[(size_t)(r0 + ty + i) * 1024 + c0 + tx];
    __syncthreads();
#pragma unroll
    for (int i = 0; i < 64; i += 4)
      wpT[(size_t)(c0 + ty + i) * 1024 + r0 + tx] = (f16)tile[tx * 65 + ty + i];
    return;
  }

  const int b = (blockIdx.x & 7) * 80 + (blockIdx.x >> 3);
  const int h = b / 40;
  const int t = b % 40;
  int m, c, nc;
  if (t < 4)       { m = t;                 c = 0;      nc = 1; }
  else if (t < 12) { int u = t - 4;  m = 4 + (u >> 1);  c = u & 1; nc = 2; }
  else if (t < 24) { int u = t - 12; m = 8 + u / 3;     c = u % 3; nc = 3; }
  else             { int u = t - 24; m = 12 + (u >> 2); c = u & 3; nc = 4; }
  const int q0 = m * 128;
  const int T = 2 * m + 2;             // k64 tiles needed (causal)
  const int kt0 = c * 8;
  const int kt1 = (kt0 + 8 < T) ? kt0 + 8 : T;
  const int maskFrom = 2 * m;          // diagonal-overlap tiles

  f16* sK = (f16*)smem;                       // [64][LROW]
  f16* sVt = sK + 64 * LROW;                  // [64][LROW]
  f16* sP = sVt + 64 * LROW;                  // [4][32*LROW]

  const int tid = threadIdx.x;
  const int wave = tid >> 6, lane = tid & 63;
  const int quad = lane >> 4, l16 = lane & 15;

  // Q fragments for both q-groups, pre-scaled by sm_scale*log2(e)
  const f16 qs = (f16)0.18033688f;  // 0.125 * log2(e)
  half8 qf[2][2];
#pragma unroll
  for (int g = 0; g < 2; g++) {
    const f16* qb = qkv + (size_t)(q0 + wave * 32 + g * 16 + l16) * 3072 +
                    h * HDIM + quad * 8;
    qf[g][0] = *(const half8*)qb;
    qf[g][1] = *(const half8*)(qb + 32);
#pragma unroll
    for (int j = 0; j < 8; j++) { qf[g][0][j] *= qs; qf[g][1][j] *= qs; }
  }

  const f16* kbase = qkv + HID + h * HDIM;
  const f16* vbase = qkv + 2 * HID + h * HDIM;
  const int ks_row = tid >> 3, ks_cc = tid & 7;
  const int vs_d = tid & 63, vs_g = tid >> 6;

  f32x4 o[2][4] = {};
  float m_i[2] = {-1e30f, -1e30f}, l_i[2] = {0.f, 0.f};
  half8 kreg[2], vreg[2];

  auto prefetch = [&](int kt) {
    const int k0 = kt * 64;
#pragma unroll
    for (int i = 0; i < 2; i++) {
      kreg[i] = *(const half8*)(kbase + (size_t)(k0 + ks_row + i * 32) * 3072 +
                                ks_cc * 8);
      half8 col;
#pragma unroll
      for (int j = 0; j < 8; j++)
        col[j] = vbase[(size_t)(k0 + (vs_g + i * 4) * 8 + j) * 3072 + vs_d];
      vreg[i] = col;
    }
  };

  prefetch(kt0);
  for (int kt = kt0; kt < kt1; kt++) {
    const int k0 = kt * 64;
#pragma unroll
    for (int i = 0; i < 2; i++) {
      *(half8*)&sK[(ks_row + i * 32) * LROW + ks_cc * 8] = kreg[i];
      *(half8*)&sVt[vs_d * LROW + (vs_g + i * 4) * 8] = vreg[i];
    }
    __syncthreads();
    if (kt + 1 < kt1) prefetch(kt + 1);

    // S^T = K Q^T ; K-frag reads shared across both q-groups
    f32x4 sacc[2][4] = {};
#pragma unroll
    for (int kb = 0; kb < 4; kb++) {
      half8 kf0 = *(const half8*)&sK[(kb * 16 + l16) * LROW + quad * 8];
      half8 kf1 = *(const half8*)&sK[(kb * 16 + l16) * LROW + 32 + quad * 8];
#pragma unroll
      for (int g = 0; g < 2; g++) {
        sacc[g][kb] = __builtin_amdgcn_mfma_f32_16x16x32_f16(kf0, qf[g][0],
                                                             sacc[g][kb], 0, 0, 0);
        sacc[g][kb] = __builtin_amdgcn_mfma_f32_16x16x32_f16(kf1, qf[g][1],
                                                             sacc[g][kb], 0, 0, 0);
      }
    }
    // causal mask on diagonal-overlap tiles
    if (kt >= maskFrom) {
#pragma unroll
      for (int g = 0; g < 2; g++) {
        const int qg = q0 + wave * 32 + g * 16 + l16;
#pragma unroll
        for (int kb = 0; kb < 4; kb++) {
          int kg = k0 + kb * 16 + quad * 4;
#pragma unroll
          for (int r = 0; r < 4; r++)
            if (kg + r > qg) sacc[g][kb][r] = -1e30f;
        }
      }
    }
    // online softmax per q-group, defer-max (skip rescale unless the tile
    // max exceeds the running max by >8 in log2 units; P then bounded 2^8)
#pragma unroll
    for (int g = 0; g < 2; g++) {
      float mx = -1e30f;
#pragma unroll
      for (int kb = 0; kb < 4; kb++)
#pragma unroll
        for (int r = 0; r < 4; r++) mx = fmaxf(mx, sacc[g][kb][r]);
      mx = fmaxf(mx, __shfl_xor(mx, 16));
      mx = fmaxf(mx, __shfl_xor(mx, 32));
      if (!__all(mx <= m_i[g] + 8.f)) {
        const float mnew = fmaxf(m_i[g], mx);
        const float alpha = exp2f(m_i[g] - mnew);
        l_i[g] *= alpha;
#pragma unroll
        for (int j = 0; j < 4; j++)
#pragma unroll
          for (int r = 0; r < 4; r++) o[g][j][r] *= alpha;
        m_i[g] = mnew;
      }
      float rs = 0.f;
#pragma unroll
      for (int kb = 0; kb < 4; kb++)
#pragma unroll
        for (int r = 0; r < 4; r++) {
          float p = exp2f(sacc[g][kb][r] - m_i[g]);
          sacc[g][kb][r] = p;
          rs += p;
        }
      rs += __shfl_xor(rs, 16);
      rs += __shfl_xor(rs, 32);
      l_i[g] += rs;
      // P store (wave-private LDS, in-order within wave) — half4 b64 writes
      f16* pw = &sP[wave * 32 * LROW + (g * 16 + l16) * LROW];
#pragma unroll
      for (int kb = 0; kb < 4; kb++) {
        half4 pv;
#pragma unroll
        for (int r = 0; r < 4; r++) pv[r] = (f16)sacc[g][kb][r];
        *(half4*)&pw[kb * 16 + quad * 4] = pv;
      }
    }
    // O^T += V^T P^T ; P fragments hoisted (j-invariant), V-frag reads
    // shared across both q-groups
    half8 pf[2][2];
#pragma unroll
    for (int g = 0; g < 2; g++) {
      pf[g][0] = *(const half8*)&sP[wave * 32 * LROW + (g * 16 + l16) * LROW + quad * 8];
      pf[g][1] = *(const half8*)&sP[wave * 32 * LROW + (g * 16 + l16) * LROW + 32 + quad * 8];
    }
#pragma unroll
    for (int j = 0; j < 4; j++) {
      half8 vf0 = *(const half8*)&sVt[(j * 16 + l16) * LROW + quad * 8];
      half8 vf1 = *(const half8*)&sVt[(j * 16 + l16) * LROW + 32 + quad * 8];
#pragma unroll
      for (int g = 0; g < 2; g++) {
        o[g][j] = __builtin_amdgcn_mfma_f32_16x16x32_f16(vf0, pf[g][0], o[g][j], 0, 0, 0);
        o[g][j] = __builtin_amdgcn_mfma_f32_16x16x32_f16(vf1, pf[g][1], o[g][j], 0, 0, 0);
      }
    }
    __syncthreads();
  }

  if (nc == 1) {
#pragma unroll
    for (int g = 0; g < 2; g++) {
      const float inv = 1.f / l_i[g];
      f16* orow =
          out + (size_t)(q0 + wave * 32 + g * 16 + l16) * HID + h * HDIM;
#pragma unroll
      for (int j = 0; j < 4; j++) {
        half4 hv;
#pragma unroll
        for (int r = 0; r < 4; r++) hv[r] = (f16)(o[g][j][r] * inv);
        *(half4*)&orow[j * 16 + quad * 4] = hv;
      }
    }
  } else {
    // per-head 36 slots: m4..7 ->(m-4)*2, m8..11 ->8+(m-8)*3, m12..15 ->20+(m-12)*4
    int base;
    if (m < 8)       base = (m - 4) * 2;
    else if (m < 12) base = 8 + (m - 8) * 3;
    else             base = 20 + (m - 12) * 4;
    const int slot = h * 36 + base + c;
#pragma unroll
    for (int g = 0; g < 2; g++) {
      const int qrow = wave * 32 + g * 16 + l16;
      f16* op = Opart + (size_t)slot * 8192 + qrow * 64;
#pragma unroll
      for (int j = 0; j < 4; j++) {
        half4 hv;
#pragma unroll
        for (int r = 0; r < 4; r++) hv[r] = (f16)o[g][j][r];
        *(half4*)&op[j * 16 + quad * 4] = hv;
      }
      if (quad == 0) {
        ml[slot * 256 + qrow] = m_i[g];
        ml[slot * 256 + 128 + qrow] = l_i[g];
      }
    }
  }
}

// ---------------------------------------------------------------------------
// Combine partials for m >= 4 (slim: 1536 blocks, 4 d's per thread,
// half4-vectorized Opart loads and out store).
__global__ __launch_bounds__(256) void attn_combine(
    const f16* __restrict__ Opart, const float* __restrict__ ml,
    f16* __restrict__ out) {
  int idx = blockIdx.x * 256 + threadIdx.x;
  int d4 = (idx & 15) * 4;
  int row = (idx >> 4) & 127;
  int rest = idx >> 11;      // 0..191
  int mi = rest % 12;        // m-4
  int h = rest / 12;
  int m = 4 + mi;
  int nc = (mi < 4) ? 2 : (mi < 8) ? 3 : 4;
  int base = (mi < 4) ? mi * 2 : (mi < 8) ? 8 + (mi - 4) * 3 : 20 + (mi - 8) * 4;
  int slot0 = h * 36 + base;

  float mm[4], ll[4];
  float M = -1e30f;
#pragma unroll
  for (int cc = 0; cc < 4; cc++)
    if (cc < nc) {
      mm[cc] = ml[(slot0 + cc) * 256 + row];
      ll[cc] = ml[(slot0 + cc) * 256 + 128 + row];
      M = fmaxf(M, mm[cc]);
    }
  float L = 0.f, acc[4] = {0.f, 0.f, 0.f, 0.f};
#pragma unroll
  for (int cc = 0; cc < 4; cc++)
    if (cc < nc) {
      float w = exp2f(mm[cc] - M);
      L += w * ll[cc];
      half4 ov = *(const half4*)&Opart[(size_t)(slot0 + cc) * 8192 +
                                       row * 64 + d4];
#pragma unroll
      for (int r = 0; r < 4; r++) acc[r] += w * (float)ov[r];
    }
  const float invL = 1.f / L;
  half4 hv;
#pragma unroll
  for (int r = 0; r < 4; r++) hv[r] = (f16)(acc[r] * invL);
  *(half4*)&out[(size_t)(m * 128 + row) * HID + h * HDIM + d4] = hv;
}

// ---------------------------------------------------------------------------
extern "C" void kernel_launch(void* const* d_in, const int* in_sizes, int n_in,
                              void* d_out, int out_size, void* d_ws,
                              size_t ws_size, hipStream_t stream) {
  const float* h = (const float*)d_in[0];    // [2048,1024]
  const float* wa = (const float*)d_in[1];   // [1024,3072]
  const float* ba = (const float*)d_in[2];   // [3072]
  const float* wp = (const float*)d_in[3];   // [1024,1024]
  const float* bp = (const float*)d_in[4];   // [1024]
  float* out = (float*)d_out;                // [2048,1024] fp32

  char* ws = (char*)d_ws;
  f16* h16 = (f16*)(ws);                       //  4 MiB (dead after GEMM1)
  f16* waT = (f16*)(ws + (4u << 20));          //  6 MiB, ends 10 MiB (dead after GEMM1)
  f16* wpT = (f16*)(ws + (10u << 20));         //  2 MiB (written by attn riders)
  f16* qkv = (f16*)(ws + (12u << 20));         // 12 MiB
  f16* attn = (f16*)(ws + (24u << 20));        //  4 MiB
  f16* Opart = (f16*)(ws);                     // reuse: 576*8192*2 = 9.44 MB
  float* mlbuf = (float*)(ws + 9437184);       // 576*256*4 (inside dead waT, safe post-GEMM1)

  prologue<<<1792, 256, 0, stream>>>(h, wa, h16, waT);
  // QKV = H @ Wattn + b -> f16 ; 64x128 tiles BK=64 2-phase, 768 blocks
  gemm_f16<64, 128, true><<<dim3(24, 32), 256, 0, stream>>>(
      h16, waT, ba, qkv, SEQ, 3 * HID, HID);
  // split-K causal attention (640 blocks) + wp-transpose riders (256 blocks)
  attn_split<<<896, 256, 0, stream>>>(qkv, attn, Opart, mlbuf, wp, wpT);
  attn_combine<<<1536, 256, 0, stream>>>(Opart, mlbuf, attn);
  // OUT = attn @ Wproj + b -> fp32 ; 64x64 tiles BK=64 2-phase, 512 blocks
  gemm_f16<64, 64, false><<<dim3(16, 32), 256, 0, stream>>>(
      attn, wpT, bp, out, SEQ, HID, HID);
}